// Round 7
// baseline (390.023 us; speedup 1.0000x reference)
//
#include <hip/hip_runtime.h>
#include <hip/hip_bf16.h>
#include <math.h>

// ---------------------------------------------------------------------------
// FaceAttnProcessor forward. R6: attention K-loop pipelined (double-buffered
// K/V via global_load_lds, one barrier/tile), XOR-swizzled P layout (kills
// 8-way ds_write conflicts), exp2-domain softmax (scale folded into fma).
// GEMMs/split-K = R5. B=2, N=1024, C=768, H=12, d=64, INNER=3072.
// ---------------------------------------------------------------------------

#define C_DIM 768
#define B_DIM 2
#define N_DIM 1024
#define NC_DIM 1040
#define L_DIM 93
#define TEXT_LEN 77
#define INNER 3072

typedef unsigned short ushort_t;
typedef __bf16 bf16x8 __attribute__((ext_vector_type(8)));
typedef float f32x4 __attribute__((ext_vector_type(4)));

__device__ __forceinline__ ushort_t f2b(float f) {
  __hip_bfloat16 h = __float2bfloat16(f);
  return *(ushort_t*)&h;
}
__device__ __forceinline__ float b2f(ushort_t u) {
  __hip_bfloat16 h = *(__hip_bfloat16*)&u;
  return __bfloat162float(h);
}

__device__ __forceinline__ void g2lds16(const void* g, void* l) {
  __builtin_amdgcn_global_load_lds(
      (const __attribute__((address_space(1))) unsigned int*)g,
      (__attribute__((address_space(3))) unsigned int*)l, 16, 0, 0);
}

// ---------------- workspace map (byte offsets) ----------------------------
#define WX1    0u           // fp32 x1 (2048*768)
#define WX2    6291456u     // fp32 x2
#define WQKV   12582912u    // u16 qkv_b [2080][2304]; later q2b/kv2b
#define WBB1   22167552u    // u16 comb_b / attn_b / tbuf_b (25.17 MB region)
#define WG     47333376u    // u16 g_b [2048][3072]
#define WS1    59916288u    // u16 hh / x2b [2048][768]
#define WTEXT  63062016u    // u16 text_b [154][768]
#define WATT2  63298560u    // u16 attn2b [2048][768]
#define WWQKV  66444288u    // u16 wqkv_t [2304][768]
#define WWO    69983232u    // u16 wo_t   [768][768]
#define WW1    71162880u    // u16 w1_t   [6144][768]
#define WW2    80600064u    // u16 w2_t   [768][3072]
#define WCAWQ  85318656u    // u16 cawq_t [768][768]
#define WCAKV  86498304u    // u16 cakv_t [1536][768]
#define WCAWO  88857600u    // u16 cawo_t [768][768]
#define WVT1   90037248u    // u16 Vt self  [2][12][64][1088]
#define WVT2   93379584u    // u16 Vt cross [2][12][64][128]
// split-K partial slabs (6,291,456 B each, fp32 2048x768 per z):
#define WPART_WO  (WBB1 + 3145728u)
#define WPART_FF2 WBB1
#define WPART_Q2  WBB1
#define WPART_FIN WBB1
// end: 93,772,800 B

// ---------------- block reduction (256 threads = 4 waves) -----------------
__device__ __forceinline__ float block_sum(float v, float* sh) {
#pragma unroll
  for (int o = 32; o > 0; o >>= 1) v += __shfl_down(v, o);
  int lane = threadIdx.x & 63, w = threadIdx.x >> 6;
  if (lane == 0) sh[w] = v;
  __syncthreads();
  float r = sh[0] + sh[1] + sh[2] + sh[3];
  __syncthreads();
  return r;
}

// ---------------- batched weight cast+transpose ---------------------------
struct WtDesc {
  const float* src[10];
  ushort_t*    dst[10];
  int K[10];
  int N[10];
  int tilesX[10];
  int start[11];
};

__global__ __launch_bounds__(256)
void wtrans_batched(WtDesc d) {
  __shared__ float tile[64][65];
  int bid = blockIdx.x;
  int j = 0;
  while (j < 9 && bid >= d.start[j + 1]) ++j;
  int ti = bid - d.start[j];
  int K = d.K[j], N = d.N[j];
  int n0 = (ti % d.tilesX[j]) * 64, k0 = (ti / d.tilesX[j]) * 64;
  const float* in = d.src[j];
  ushort_t* out = d.dst[j];
  int t = threadIdx.x;
#pragma unroll
  for (int p = 0; p < 16; ++p) {
    int idx = t + p * 256;
    int r = idx >> 6, c = idx & 63;
    tile[r][c] = in[(size_t)(k0 + r) * N + n0 + c];
  }
  __syncthreads();
#pragma unroll
  for (int p = 0; p < 16; ++p) {
    int idx = t + p * 256;
    int r = idx >> 6, c = idx & 63;
    out[(size_t)(n0 + r) * K + k0 + c] = f2b(tile[c][r]);
  }
}

// ---------------- LN(x) and LN(face) -> comb (bf16) -----------------------
__global__ __launch_bounds__(256)
void ln_concat_kernel(const float* __restrict__ x, const float* __restrict__ enc,
                      const float* __restrict__ g, const float* __restrict__ b,
                      ushort_t* __restrict__ comb) {
  __shared__ float sh[4];
  int r = blockIdx.x;
  int bb = r / NC_DIM, i = r % NC_DIM;
  const float* src = (i < N_DIM)
      ? (x   + ((size_t)bb * N_DIM + i) * C_DIM)
      : (enc + ((size_t)bb * L_DIM + TEXT_LEN + (i - N_DIM)) * C_DIM);
  float v[3];
#pragma unroll
  for (int j = 0; j < 3; ++j) v[j] = src[threadIdx.x + j * 256];
  float mean = block_sum(v[0] + v[1] + v[2], sh) * (1.f / C_DIM);
  float sq = 0.f;
#pragma unroll
  for (int j = 0; j < 3; ++j) { float d = v[j] - mean; sq += d * d; }
  float rstd = rsqrtf(block_sum(sq, sh) * (1.f / C_DIM) + 1e-5f);
  ushort_t* dst = comb + (size_t)r * C_DIM;
#pragma unroll
  for (int j = 0; j < 3; ++j) {
    int c = threadIdx.x + j * 256;
    dst[c] = f2b((v[j] - mean) * rstd * g[c] + b[c]);
  }
}

// ---------------- bf16 MFMA GEMM, double-buffered, optional split-K --------
__global__ __launch_bounds__(256)
void gemm_bf16(const ushort_t* __restrict__ A, const ushort_t* __restrict__ Bt,
               float* __restrict__ Out, ushort_t* __restrict__ Ob,
               float* __restrict__ Part,
               int M, int N, int K, int Ksplit,
               const float* __restrict__ bias, const float* __restrict__ res,
               const float* __restrict__ alphaPtr) {
  __shared__ ushort_t sA[2][128 * 32];
  __shared__ ushort_t sB[2][128 * 32];
  int t = threadIdx.x;
  int w = t >> 6, ln = t & 63;
  int m0 = blockIdx.y * 128, n0 = blockIdx.x * 128;
  int wm = (w >> 1) * 64, wn = (w & 1) * 64;
  int lr = ln & 15, lq = ln >> 4;
  int seg_r = ln >> 2, seg_c = (ln & 3) * 8;
  int kbeg = blockIdx.z * Ksplit;
  int kend = kbeg + Ksplit; if (kend > K) kend = K;

  f32x4 acc[4][4];
#pragma unroll
  for (int mi = 0; mi < 4; ++mi)
#pragma unroll
    for (int ni = 0; ni < 4; ++ni) acc[mi][ni] = (f32x4){0.f, 0.f, 0.f, 0.f};

#define STAGE(k0_, buf_)                                                     \
  do {                                                                       \
    _Pragma("unroll") for (int l = 0; l < 2; ++l) {                          \
      int s = w * 2 + l;                                                     \
      int arow = m0 + s * 16 + seg_r;                                        \
      arow = arow < M ? arow : M - 1;                                        \
      g2lds16(A + (size_t)arow * K + (k0_) + seg_c, &sA[buf_][s * 512]);     \
      int nrow = n0 + s * 16 + seg_r;                                        \
      g2lds16(Bt + (size_t)nrow * K + (k0_) + seg_c, &sB[buf_][s * 512]);    \
    }                                                                        \
  } while (0)

  STAGE(kbeg, 0);
  __syncthreads();
  int cur = 0;
  for (int k0 = kbeg; k0 < kend; k0 += 32) {
    if (k0 + 32 < kend) STAGE(k0 + 32, cur ^ 1);   // prefetch next tile
    bf16x8 af[4], bfr[4];
#pragma unroll
    for (int mi = 0; mi < 4; ++mi)
      af[mi] = *(const bf16x8*)&sA[cur][(wm + mi * 16 + lr) * 32 + lq * 8];
#pragma unroll
    for (int ni = 0; ni < 4; ++ni)
      bfr[ni] = *(const bf16x8*)&sB[cur][(wn + ni * 16 + lr) * 32 + lq * 8];
#pragma unroll
    for (int mi = 0; mi < 4; ++mi)
#pragma unroll
      for (int ni = 0; ni < 4; ++ni)
        acc[mi][ni] = __builtin_amdgcn_mfma_f32_16x16x32_bf16(
            af[mi], bfr[ni], acc[mi][ni], 0, 0, 0);
    __syncthreads();
    cur ^= 1;
  }
#undef STAGE

  if (Part) {
    float* P = Part + (size_t)blockIdx.z * M * N;
#pragma unroll
    for (int mi = 0; mi < 4; ++mi)
#pragma unroll
      for (int ni = 0; ni < 4; ++ni) {
        int col = n0 + wn + ni * 16 + lr;
#pragma unroll
        for (int r = 0; r < 4; ++r) {
          int row = m0 + wm + mi * 16 + lq * 4 + r;
          if (row < M) P[(size_t)row * N + col] = acc[mi][ni][r];
        }
      }
  } else {
    float f = alphaPtr ? tanhf(alphaPtr[0]) : 1.0f;
#pragma unroll
    for (int mi = 0; mi < 4; ++mi)
#pragma unroll
      for (int ni = 0; ni < 4; ++ni) {
        int col = n0 + wn + ni * 16 + lr;
        float bv = bias ? bias[col] : 0.f;
#pragma unroll
        for (int r = 0; r < 4; ++r) {
          int row = m0 + wm + mi * 16 + lq * 4 + r;
          if (row < M) {
            float val = acc[mi][ni][r] + bv;
            if (res) val = res[(size_t)row * N + col] + f * val;
            if (Out) Out[(size_t)row * N + col] = val;
            if (Ob)  Ob[(size_t)row * N + col] = f2b(val);
          }
        }
      }
  }
}

// ---------------- split-K reduce epilogue ----------------------------------
__global__ __launch_bounds__(256)
void splitk_epi(const float* __restrict__ Part, int nz, float* __restrict__ Out,
                ushort_t* __restrict__ Ob, int MN, int N,
                const float* __restrict__ bias, const float* __restrict__ res,
                const float* __restrict__ alphaPtr) {
  int idx = (blockIdx.x * 256 + threadIdx.x) * 4;
  if (idx >= MN) return;
  float f = alphaPtr ? tanhf(alphaPtr[0]) : 1.0f;
  float v[4] = {0.f, 0.f, 0.f, 0.f};
  for (int z = 0; z < nz; ++z) {
    float4 a = *(const float4*)&Part[(size_t)z * MN + idx];
    v[0] += a.x; v[1] += a.y; v[2] += a.z; v[3] += a.w;
  }
  if (bias) {
    int col = idx % N;
    float4 bb = *(const float4*)&bias[col];
    v[0] += bb.x; v[1] += bb.y; v[2] += bb.z; v[3] += bb.w;
  }
  if (res) {
    float4 rr = *(const float4*)&res[idx];
    v[0] = rr.x + f * v[0]; v[1] = rr.y + f * v[1];
    v[2] = rr.z + f * v[2]; v[3] = rr.w + f * v[3];
  }
  if (Out) *(float4*)&Out[idx] = make_float4(v[0], v[1], v[2], v[3]);
  if (Ob) {
    ushort4 o;
    o.x = f2b(v[0]); o.y = f2b(v[1]); o.z = f2b(v[2]); o.w = f2b(v[3]);
    *(ushort4*)&Ob[idx] = o;
  }
}

// ---------------- fused wo-epilogue + double layernorm --------------------
__global__ __launch_bounds__(256)
void woepi_ln_kernel(const float* __restrict__ Part, int nz,
                     const float* __restrict__ bias, const float* __restrict__ xres,
                     const float* __restrict__ alphaPtr, float* __restrict__ x1,
                     const float* __restrict__ g1, const float* __restrict__ b1,
                     const float* __restrict__ g2, const float* __restrict__ b2,
                     ushort_t* __restrict__ hh) {
  __shared__ float sh[4];
  int row = blockIdx.x;
  const int MN = B_DIM * N_DIM * C_DIM;
  float f = tanhf(alphaPtr[0]);
  float v[3];
#pragma unroll
  for (int j = 0; j < 3; ++j) {
    int c = threadIdx.x + j * 256;
    float s = 0.f;
    for (int z = 0; z < nz; ++z) s += Part[(size_t)z * MN + (size_t)row * C_DIM + c];
    s += bias[c];
    float xv = xres[(size_t)row * C_DIM + c] + f * s;
    x1[(size_t)row * C_DIM + c] = xv;
    v[j] = xv;
  }
  float mean = block_sum(v[0] + v[1] + v[2], sh) * (1.f / C_DIM);
  float sq = 0.f;
#pragma unroll
  for (int j = 0; j < 3; ++j) { float d = v[j] - mean; sq += d * d; }
  float rstd = rsqrtf(block_sum(sq, sh) * (1.f / C_DIM) + 1e-5f);
  float y[3];
#pragma unroll
  for (int j = 0; j < 3; ++j) {
    int c = threadIdx.x + j * 256;
    y[j] = (v[j] - mean) * rstd * g1[c] + b1[c];
  }
  float mean2 = block_sum(y[0] + y[1] + y[2], sh) * (1.f / C_DIM);
  sq = 0.f;
#pragma unroll
  for (int j = 0; j < 3; ++j) { float d = y[j] - mean2; sq += d * d; }
  float rstd2 = rsqrtf(block_sum(sq, sh) * (1.f / C_DIM) + 1e-5f);
#pragma unroll
  for (int j = 0; j < 3; ++j) {
    int c = threadIdx.x + j * 256;
    hh[(size_t)row * C_DIM + c] = f2b((y[j] - mean2) * rstd2 * g2[c] + b2[c]);
  }
}

// ---------------- V transpose: strided bf16 [key][64] -> Vt [dv][Nkp] -----
__global__ __launch_bounds__(256)
void vtrans_kernel(const ushort_t* __restrict__ V, ushort_t* __restrict__ Vt,
                   int rows_per_b, int stride, int Nk, int Nkp) {
  __shared__ ushort_t tile[64][68];
  int k0 = blockIdx.x * 64;
  int h = blockIdx.y, b = blockIdx.z;
  int t = threadIdx.x;
#pragma unroll
  for (int p = 0; p < 4; ++p) {
    int r = p * 16 + (t >> 4), c = (t & 15) * 4;
    int key = k0 + r;
    ushort4 u = make_ushort4(0, 0, 0, 0);
    if (key < Nk)
      u = *(const ushort4*)&V[((size_t)(b * rows_per_b + key)) * stride + h * 64 + c];
    *(ushort4*)&tile[r][c] = u;
  }
  __syncthreads();
  size_t base = ((size_t)(b * 12 + h)) * 64 * Nkp;
#pragma unroll
  for (int p = 0; p < 4; ++p) {
    int dv = p * 16 + (t >> 4), kc = (t & 15) * 4;
    ushort4 u;
    u.x = tile[kc + 0][dv]; u.y = tile[kc + 1][dv];
    u.z = tile[kc + 2][dv]; u.w = tile[kc + 3][dv];
    *(ushort4*)&Vt[base + (size_t)dv * Nkp + k0 + kc] = u;
  }
}

// ---------------- MFMA flash attention (R6: pipelined + swizzled P) -------
// Block = (64-q tile, h, b); 4 waves. Double-buffered K/V staging: prefetch
// tile kt+1 at top of iter, compute kt, one barrier drains. P stored per-wave
// with XOR swizzle (kin ^ quad<<3) to break ds_write 8-way conflicts.
// Softmax in exp2 domain: scale*log2e folded into the fma feeding exp2.
__global__ __launch_bounds__(256)
void attn_mfma(const ushort_t* __restrict__ Q, const ushort_t* __restrict__ K,
               const ushort_t* __restrict__ Vt, ushort_t* __restrict__ O,
               int q_rows_per_b, int kv_rows_per_b, int Nk, int Nkp,
               int qstride, int kstride) {
  __shared__ ushort_t sQ[4096];        // [2 kstep][64 q][32]
  __shared__ ushort_t sK[2][4096];     // double-buffered key tile
  __shared__ ushort_t sV[2][4096];     // double-buffered value tile (dv-major)
  __shared__ ushort_t sP[4][1024];     // per-wave P [2 step][16 q][32 k], swizzled
  const float scale = 0.18033688011112042f;   // 1/8 * log2(e)
  int t = threadIdx.x;
  int w = t >> 6, ln = t & 63;
  int col = ln & 15, quad = ln >> 4;
  int b = blockIdx.z, h = blockIdx.y, q0 = blockIdx.x * 64;
  size_t vt_base = ((size_t)(b * 12 + h)) * 64 * Nkp;

#define STAGE_KV(kt_, bb_)                                                    \
  do {                                                                        \
    _Pragma("unroll") for (int s = 0; s < 2; ++s) {                           \
      int key = (kt_) * 64 + w * 16 + (ln >> 2);                              \
      g2lds16(K + (size_t)(b * kv_rows_per_b + key) * kstride                 \
                + h * 64 + s * 32 + (ln & 3) * 8,                             \
              (char*)sK[bb_] + s * 4096 + w * 1024);                          \
      int dv = w * 16 + (ln >> 2);                                            \
      g2lds16(Vt + vt_base + (size_t)dv * Nkp                                 \
                + (kt_) * 64 + s * 32 + (ln & 3) * 8,                         \
              (char*)sV[bb_] + s * 4096 + w * 1024);                          \
    }                                                                         \
  } while (0)

  // ---- stage Q + first K/V tile ----
#pragma unroll
  for (int s = 0; s < 2; ++s) {
    int r = q0 + w * 16 + (ln >> 2);
    g2lds16(Q + (size_t)(b * q_rows_per_b + r) * qstride + h * 64 + s * 32 + (ln & 3) * 8,
            (char*)sQ + s * 4096 + w * 1024);
  }
  STAGE_KV(0, 0);
  __syncthreads();
  bf16x8 qa[2];
#pragma unroll
  for (int s = 0; s < 2; ++s)
    qa[s] = *(const bf16x8*)&sQ[s * 2048 + (w * 16 + col) * 32 + quad * 8];

  f32x4 oacc[4];
#pragma unroll
  for (int i = 0; i < 4; ++i) oacc[i] = (f32x4){0.f, 0.f, 0.f, 0.f};
  float m_i[4], l_i[4];
#pragma unroll
  for (int r = 0; r < 4; ++r) { m_i[r] = -1e30f; l_i[r] = 0.f; }

  ushort_t* sPw = sP[w];
  int ntiles = Nkp >> 6;
  int bb = 0;

  for (int kt = 0; kt < ntiles; ++kt) {
    if (kt + 1 < ntiles) STAGE_KV(kt + 1, bb ^ 1);   // async prefetch

    // ---- S = Q K^T (raw scores) ----
    f32x4 cs[4];
#pragma unroll
    for (int nblk = 0; nblk < 4; ++nblk) {
      cs[nblk] = (f32x4){0.f, 0.f, 0.f, 0.f};
#pragma unroll
      for (int s = 0; s < 2; ++s) {
        bf16x8 kb = *(const bf16x8*)&sK[bb][s * 2048 + (nblk * 16 + col) * 32 + quad * 8];
        cs[nblk] = __builtin_amdgcn_mfma_f32_16x16x32_bf16(qa[s], kb, cs[nblk], 0, 0, 0);
      }
    }
    // ---- mask only the partial last tile (select kills garbage/NaN) ----
    if (kt * 64 + 64 > Nk) {
#pragma unroll
      for (int nblk = 0; nblk < 4; ++nblk) {
        bool valid = (kt * 64 + nblk * 16 + col) < Nk;
#pragma unroll
        for (int r = 0; r < 4; ++r)
          cs[nblk][r] = valid ? cs[nblk][r] : -1e30f;
      }
    }
    // ---- online softmax (exp2 domain; scale folded into fma) ----
#pragma unroll
    for (int r = 0; r < 4; ++r) {
      float rm = fmaxf(fmaxf(cs[0][r], cs[1][r]), fmaxf(cs[2][r], cs[3][r]));
#pragma unroll
      for (int o = 1; o < 16; o <<= 1) rm = fmaxf(rm, __shfl_xor(rm, o));
      float mnew = fmaxf(m_i[r], rm * scale);
      float alpha = exp2f(m_i[r] - mnew);
      float ps = 0.f;
      int row = quad * 4 + r;
#pragma unroll
      for (int nblk = 0; nblk < 4; ++nblk) {
        float p = exp2f(fmaf(cs[nblk][r], scale, -mnew));
        ps += p;
        int kin = (nblk & 1) * 16 + col;
        sPw[(nblk >> 1) * 512 + row * 32 + (kin ^ (quad << 3))] = f2b(p);
      }
#pragma unroll
      for (int o = 1; o < 16; o <<= 1) ps += __shfl_xor(ps, o);
      l_i[r] = l_i[r] * alpha + ps;
      m_i[r] = mnew;
#pragma unroll
      for (int nblk = 0; nblk < 4; ++nblk) oacc[nblk][r] *= alpha;
    }
    // ---- O += P V ----
#pragma unroll
    for (int s = 0; s < 2; ++s) {
      bf16x8 pa = *(const bf16x8*)&sPw[s * 512 + col * 32 + ((quad ^ ((col >> 2) & 3)) << 3)];
#pragma unroll
      for (int nblk = 0; nblk < 4; ++nblk) {
        bf16x8 vb = *(const bf16x8*)&sV[bb][s * 2048 + (nblk * 16 + col) * 32 + quad * 8];
        oacc[nblk] = __builtin_amdgcn_mfma_f32_16x16x32_bf16(pa, vb, oacc[nblk], 0, 0, 0);
      }
    }
    if (kt + 1 < ntiles) __syncthreads();   // drains prefetch + protects reuse
    bb ^= 1;
  }
#undef STAGE_KV

  // ---- epilogue: O[q][dv] = oacc / l ----
#pragma unroll
  for (int r = 0; r < 4; ++r) {
    float inv = 1.f / l_i[r];
    int row = b * N_DIM + q0 + w * 16 + quad * 4 + r;
#pragma unroll
    for (int nblk = 0; nblk < 4; ++nblk)
      O[(size_t)row * C_DIM + h * 64 + nblk * 16 + col] = f2b(oacc[nblk][r] * inv);
  }
}

// ---------------- GEGLU ----------------------------------------------------
__global__ __launch_bounds__(256)
void geglu_kernel(const ushort_t* __restrict__ tbuf, ushort_t* __restrict__ g) {
  int idx = blockIdx.x * 256 + threadIdx.x;
  int r = idx / INNER, c = idx % INNER;
  float a = b2f(tbuf[(size_t)r * (2 * INNER) + c]);
  float x = b2f(tbuf[(size_t)r * (2 * INNER) + INNER + c]);
  float ge = 0.5f * x * (1.f + erff(x * 0.70710678118654752f));
  g[idx] = f2b(a * ge);
}

// ---------------- text gather ----------------------------------------------
__global__ __launch_bounds__(256)
void gather_text_kernel(const float* __restrict__ enc, ushort_t* __restrict__ out) {
  int r = blockIdx.x;
  int bb = r / TEXT_LEN, j = r % TEXT_LEN;
  const float* src = enc + ((size_t)bb * L_DIM + j) * C_DIM;
  ushort_t* dst = out + (size_t)r * C_DIM;
#pragma unroll
  for (int l = 0; l < 3; ++l) {
    int c = threadIdx.x + l * 256;
    dst[c] = f2b(src[c]);
  }
}

// ---------------------------------------------------------------------------
extern "C" void kernel_launch(void* const* d_in, const int* in_sizes, int n_in,
                              void* d_out, int out_size, void* d_ws, size_t ws_size,
                              hipStream_t stream) {
  const float* x        = (const float*)d_in[0];
  const float* enc      = (const float*)d_in[1];
  const float* ln1_g    = (const float*)d_in[2];
  const float* ln1_b    = (const float*)d_in[3];
  const float* ln2_g    = (const float*)d_in[4];
  const float* ln2_b    = (const float*)d_in[5];
  const float* sa_wq    = (const float*)d_in[6];
  const float* sa_wk    = (const float*)d_in[7];
  const float* sa_wv    = (const float*)d_in[8];
  const float* sa_wo    = (const float*)d_in[9];
  const float* sa_wo_b  = (const float*)d_in[10];
  const float* ff_ln_g  = (const float*)d_in[11];
  const float* ff_ln_b  = (const float*)d_in[12];
  const float* ff_w1    = (const float*)d_in[13];
  const float* ff_w2    = (const float*)d_in[14];
  const float* a_attn   = (const float*)d_in[15];
  const float* a_dense  = (const float*)d_in[16];
  const float* ca_wq    = (const float*)d_in[17];
  const float* ca_wk    = (const float*)d_in[18];
  const float* ca_wv    = (const float*)d_in[19];
  const float* ca_wo    = (const float*)d_in[20];
  const float* ca_wo_b  = (const float*)d_in[21];

  char* ws = (char*)d_ws;
  float*    x1     = (float*)(ws + WX1);
  float*    x2     = (float*)(ws + WX2);
  ushort_t* qkv_b  = (ushort_t*)(ws + WQKV);
  ushort_t* q2b    = (ushort_t*)(ws + WQKV);
  ushort_t* kv2b   = (ushort_t*)(ws + WQKV + 3145728u);
  ushort_t* comb_b = (ushort_t*)(ws + WBB1);
  ushort_t* attn_b = (ushort_t*)(ws + WBB1);
  ushort_t* tbuf_b = (ushort_t*)(ws + WBB1);
  ushort_t* g_b    = (ushort_t*)(ws + WG);
  ushort_t* hh     = (ushort_t*)(ws + WS1);
  ushort_t* x2b    = (ushort_t*)(ws + WS1);
  ushort_t* text_b = (ushort_t*)(ws + WTEXT);
  ushort_t* attn2b = (ushort_t*)(ws + WATT2);
  ushort_t* wqkv_t = (ushort_t*)(ws + WWQKV);
  ushort_t* wo_t   = (ushort_t*)(ws + WWO);
  ushort_t* w1_t   = (ushort_t*)(ws + WW1);
  ushort_t* w2_t   = (ushort_t*)(ws + WW2);
  ushort_t* cawq_t = (ushort_t*)(ws + WCAWQ);
  ushort_t* cakv_t = (ushort_t*)(ws + WCAKV);
  ushort_t* cawo_t = (ushort_t*)(ws + WCAWO);
  ushort_t* vt1    = (ushort_t*)(ws + WVT1);
  ushort_t* vt2    = (ushort_t*)(ws + WVT2);
  float* part_wo  = (float*)(ws + WPART_WO);
  float* part_ff2 = (float*)(ws + WPART_FF2);
  float* part_q2  = (float*)(ws + WPART_Q2);
  float* part_fin = (float*)(ws + WPART_FIN);
  float* out = (float*)d_out;

  const int Mc = B_DIM * NC_DIM;   // 2080
  const int Mx = B_DIM * N_DIM;    // 2048
  const int Mt = B_DIM * TEXT_LEN; // 154
  const int MNx = Mx * C_DIM;      // 1,572,864

  // ---- batched weight transposes ----
  WtDesc wd;
  const float* srcs[10] = {sa_wq, sa_wk, sa_wv, sa_wo, ca_wq, ca_wk, ca_wv, ca_wo, ff_w1, ff_w2};
  ushort_t* dsts[10] = {wqkv_t, wqkv_t + 589824, wqkv_t + 2 * 589824, wo_t,
                        cawq_t, cakv_t, cakv_t + 589824, cawo_t, w1_t, w2_t};
  int Ks[10] = {768, 768, 768, 768, 768, 768, 768, 768, 768, 3072};
  int Ns[10] = {768, 768, 768, 768, 768, 768, 768, 768, 6144, 768};
  int total = 0;
  for (int j = 0; j < 10; ++j) {
    wd.src[j] = srcs[j]; wd.dst[j] = dsts[j];
    wd.K[j] = Ks[j]; wd.N[j] = Ns[j];
    wd.tilesX[j] = Ns[j] / 64;
    wd.start[j] = total;
    total += (Ns[j] / 64) * (Ks[j] / 64);
  }
  wd.start[10] = total;   // 2880

  wtrans_batched<<<total, 256, 0, stream>>>(wd);
  ln_concat_kernel<<<Mc, 256, 0, stream>>>(x, enc, ln1_g, ln1_b, comb_b);
  gemm_bf16<<<dim3(18, 17, 1), 256, 0, stream>>>(
      comb_b, wqkv_t, nullptr, qkv_b, nullptr, Mc, 2304, 768, 768,
      nullptr, nullptr, nullptr);
  vtrans_kernel<<<dim3(17, 12, B_DIM), 256, 0, stream>>>(
      qkv_b + 1536, vt1, NC_DIM, 2304, NC_DIM, 1088);
  attn_mfma<<<dim3(N_DIM / 64, 12, B_DIM), 256, 0, stream>>>(
      qkv_b + 0, qkv_b + 768, vt1, attn_b, NC_DIM, NC_DIM, NC_DIM, 1088, 2304, 2304);
  // wo: split-K 3 x 256 -> partials -> fused epilogue+double-LN
  gemm_bf16<<<dim3(6, 16, 3), 256, 0, stream>>>(
      attn_b, wo_t, nullptr, nullptr, part_wo, Mx, 768, 768, 256,
      nullptr, nullptr, nullptr);
  woepi_ln_kernel<<<Mx, 256, 0, stream>>>(
      part_wo, 3, sa_wo_b, x, a_attn, x1, ln2_g, ln2_b, ff_ln_g, ff_ln_b, hh);
  gemm_bf16<<<dim3(48, 16, 1), 256, 0, stream>>>(
      hh, w1_t, nullptr, tbuf_b, nullptr, Mx, 6144, 768, 768,
      nullptr, nullptr, nullptr);
  geglu_kernel<<<(Mx * INNER) / 256, 256, 0, stream>>>(tbuf_b, g_b);
  // ff2: split-K 4 x 768
  gemm_bf16<<<dim3(6, 16, 4), 256, 0, stream>>>(
      g_b, w2_t, nullptr, nullptr, part_ff2, Mx, 768, 3072, 768,
      nullptr, nullptr, nullptr);
  splitk_epi<<<MNx / 1024, 256, 0, stream>>>(
      part_ff2, 4, x2, x2b, MNx, 768, nullptr, x1, a_dense);
  gather_text_kernel<<<Mt, 256, 0, stream>>>(enc, text_b);
  // q2: split-K 3 x 256
  gemm_bf16<<<dim3(6, 16, 3), 256, 0, stream>>>(
      x2b, cawq_t, nullptr, nullptr, part_q2, Mx, 768, 768, 256,
      nullptr, nullptr, nullptr);
  splitk_epi<<<MNx / 1024, 256, 0, stream>>>(
      part_q2, 3, nullptr, q2b, MNx, 768, nullptr, nullptr, nullptr);
  gemm_bf16<<<dim3(12, 2, 1), 256, 0, stream>>>(
      text_b, cakv_t, nullptr, kv2b, nullptr, Mt, 1536, 768, 768,
      nullptr, nullptr, nullptr);
  vtrans_kernel<<<dim3(2, 12, B_DIM), 256, 0, stream>>>(
      kv2b + 768, vt2, TEXT_LEN, 1536, TEXT_LEN, 128);
  attn_mfma<<<dim3(N_DIM / 64, 12, B_DIM), 256, 0, stream>>>(
      q2b, kv2b + 0, vt2, attn2b, N_DIM, TEXT_LEN, TEXT_LEN, 128, 768, 1536);
  // final: split-K 3 x 256
  gemm_bf16<<<dim3(6, 16, 3), 256, 0, stream>>>(
      attn2b, cawo_t, nullptr, nullptr, part_fin, Mx, 768, 768, 256,
      nullptr, nullptr, nullptr);
  splitk_epi<<<MNx / 1024, 256, 0, stream>>>(
      part_fin, 3, out, nullptr, MNx, 768, ca_wo_b, x2, nullptr);
}

// Round 8
// 376.380 us; speedup vs baseline: 1.0362x; 1.0362x over previous
//
#include <hip/hip_runtime.h>
#include <hip/hip_bf16.h>
#include <math.h>

// ---------------------------------------------------------------------------
// FaceAttnProcessor forward. R7: key-split self-attention (4 chunks -> fp32
// partials + merge kernel) with static-max exp2 softmax (no shuffle chains
// in the K-loop). Cross-attn same kernel, nchunk=1 (in-kernel normalize).
// Split-K GEMMs at z=4. B=2, N=1024, C=768, H=12, d=64, INNER=3072.
// ---------------------------------------------------------------------------

#define C_DIM 768
#define B_DIM 2
#define N_DIM 1024
#define NC_DIM 1040
#define L_DIM 93
#define TEXT_LEN 77
#define INNER 3072
#define MNX 1572864   // 2048*768

typedef unsigned short ushort_t;
typedef __bf16 bf16x8 __attribute__((ext_vector_type(8)));
typedef float f32x4 __attribute__((ext_vector_type(4)));

__device__ __forceinline__ ushort_t f2b(float f) {
  __hip_bfloat16 h = __float2bfloat16(f);
  return *(ushort_t*)&h;
}
__device__ __forceinline__ float b2f(ushort_t u) {
  __hip_bfloat16 h = *(__hip_bfloat16*)&u;
  return __bfloat162float(h);
}

__device__ __forceinline__ void g2lds16(const void* g, void* l) {
  __builtin_amdgcn_global_load_lds(
      (const __attribute__((address_space(1))) unsigned int*)g,
      (__attribute__((address_space(3))) unsigned int*)l, 16, 0, 0);
}

// ---------------- workspace map (byte offsets) ----------------------------
#define WX1    0u           // fp32 x1 (2048*768)
#define WX2    6291456u     // fp32 x2
#define WQKV   12582912u    // u16 qkv_b [2080][2304]; later q2b/kv2b
#define WBB1   22167552u    // 25.17 MB: comb_b / Opart[4] / part slabs / tbuf_b
#define WG     47333376u    // 12.58 MB: lbuf + attn_b (phase A) / g_b (phase C)
#define WS1    59916288u    // u16 hh / x2b [2048][768]
#define WTEXT  63062016u    // u16 text_b [154][768]
#define WATT2  63298560u    // u16 attn2b [2048][768]
#define WWQKV  66444288u    // u16 wqkv_t [2304][768]
#define WWO    69983232u    // u16 wo_t   [768][768]
#define WW1    71162880u    // u16 w1_t   [6144][768]
#define WW2    80600064u    // u16 w2_t   [768][3072]
#define WCAWQ  85318656u    // u16 cawq_t [768][768]
#define WCAKV  86498304u    // u16 cakv_t [1536][768]
#define WCAWO  88857600u    // u16 cawo_t [768][768]
#define WVT1   90037248u    // u16 Vt self  [2][12][64][1088]
#define WVT2   93379584u    // u16 Vt cross [2][12][64][128]
// overlays:
#define WOPART WBB1                 // fp32 Opart[4][2048][768] = 25,165,824 (exact)
#define WLBUF  WG                   // fp32 lbuf[4][2048][12] = 393,216
#define WATTN  (WG + 524288u)       // u16 attn_b [2048][768] (dead before g_b)
#define WPART  WBB1                 // fp32 part[4][2048][768] for wo/ff2/q2/fin
// end: 93,772,800 B

// ---------------- block reduction (256 threads = 4 waves) -----------------
__device__ __forceinline__ float block_sum(float v, float* sh) {
#pragma unroll
  for (int o = 32; o > 0; o >>= 1) v += __shfl_down(v, o);
  int lane = threadIdx.x & 63, w = threadIdx.x >> 6;
  if (lane == 0) sh[w] = v;
  __syncthreads();
  float r = sh[0] + sh[1] + sh[2] + sh[3];
  __syncthreads();
  return r;
}

// ---------------- batched weight cast+transpose ---------------------------
struct WtDesc {
  const float* src[10];
  ushort_t*    dst[10];
  int K[10];
  int N[10];
  int tilesX[10];
  int start[11];
};

__global__ __launch_bounds__(256)
void wtrans_batched(WtDesc d) {
  __shared__ float tile[64][65];
  int bid = blockIdx.x;
  int j = 0;
  while (j < 9 && bid >= d.start[j + 1]) ++j;
  int ti = bid - d.start[j];
  int K = d.K[j], N = d.N[j];
  int n0 = (ti % d.tilesX[j]) * 64, k0 = (ti / d.tilesX[j]) * 64;
  const float* in = d.src[j];
  ushort_t* out = d.dst[j];
  int t = threadIdx.x;
#pragma unroll
  for (int p = 0; p < 16; ++p) {
    int idx = t + p * 256;
    int r = idx >> 6, c = idx & 63;
    tile[r][c] = in[(size_t)(k0 + r) * N + n0 + c];
  }
  __syncthreads();
#pragma unroll
  for (int p = 0; p < 16; ++p) {
    int idx = t + p * 256;
    int r = idx >> 6, c = idx & 63;
    out[(size_t)(n0 + r) * K + k0 + c] = f2b(tile[c][r]);
  }
}

// ---------------- LN(x) and LN(face) -> comb (bf16) -----------------------
__global__ __launch_bounds__(256)
void ln_concat_kernel(const float* __restrict__ x, const float* __restrict__ enc,
                      const float* __restrict__ g, const float* __restrict__ b,
                      ushort_t* __restrict__ comb) {
  __shared__ float sh[4];
  int r = blockIdx.x;
  int bb = r / NC_DIM, i = r % NC_DIM;
  const float* src = (i < N_DIM)
      ? (x   + ((size_t)bb * N_DIM + i) * C_DIM)
      : (enc + ((size_t)bb * L_DIM + TEXT_LEN + (i - N_DIM)) * C_DIM);
  float v[3];
#pragma unroll
  for (int j = 0; j < 3; ++j) v[j] = src[threadIdx.x + j * 256];
  float mean = block_sum(v[0] + v[1] + v[2], sh) * (1.f / C_DIM);
  float sq = 0.f;
#pragma unroll
  for (int j = 0; j < 3; ++j) { float d = v[j] - mean; sq += d * d; }
  float rstd = rsqrtf(block_sum(sq, sh) * (1.f / C_DIM) + 1e-5f);
  ushort_t* dst = comb + (size_t)r * C_DIM;
#pragma unroll
  for (int j = 0; j < 3; ++j) {
    int c = threadIdx.x + j * 256;
    dst[c] = f2b((v[j] - mean) * rstd * g[c] + b[c]);
  }
}

// ---------------- bf16 MFMA GEMM, double-buffered, optional split-K --------
__global__ __launch_bounds__(256)
void gemm_bf16(const ushort_t* __restrict__ A, const ushort_t* __restrict__ Bt,
               float* __restrict__ Out, ushort_t* __restrict__ Ob,
               float* __restrict__ Part,
               int M, int N, int K, int Ksplit,
               const float* __restrict__ bias, const float* __restrict__ res,
               const float* __restrict__ alphaPtr) {
  __shared__ ushort_t sA[2][128 * 32];
  __shared__ ushort_t sB[2][128 * 32];
  int t = threadIdx.x;
  int w = t >> 6, ln = t & 63;
  int m0 = blockIdx.y * 128, n0 = blockIdx.x * 128;
  int wm = (w >> 1) * 64, wn = (w & 1) * 64;
  int lr = ln & 15, lq = ln >> 4;
  int seg_r = ln >> 2, seg_c = (ln & 3) * 8;
  int kbeg = blockIdx.z * Ksplit;
  int kend = kbeg + Ksplit; if (kend > K) kend = K;

  f32x4 acc[4][4];
#pragma unroll
  for (int mi = 0; mi < 4; ++mi)
#pragma unroll
    for (int ni = 0; ni < 4; ++ni) acc[mi][ni] = (f32x4){0.f, 0.f, 0.f, 0.f};

#define STAGE(k0_, buf_)                                                     \
  do {                                                                       \
    _Pragma("unroll") for (int l = 0; l < 2; ++l) {                          \
      int s = w * 2 + l;                                                     \
      int arow = m0 + s * 16 + seg_r;                                        \
      arow = arow < M ? arow : M - 1;                                        \
      g2lds16(A + (size_t)arow * K + (k0_) + seg_c, &sA[buf_][s * 512]);     \
      int nrow = n0 + s * 16 + seg_r;                                        \
      g2lds16(Bt + (size_t)nrow * K + (k0_) + seg_c, &sB[buf_][s * 512]);    \
    }                                                                        \
  } while (0)

  STAGE(kbeg, 0);
  __syncthreads();
  int cur = 0;
  for (int k0 = kbeg; k0 < kend; k0 += 32) {
    if (k0 + 32 < kend) STAGE(k0 + 32, cur ^ 1);   // prefetch next tile
    bf16x8 af[4], bfr[4];
#pragma unroll
    for (int mi = 0; mi < 4; ++mi)
      af[mi] = *(const bf16x8*)&sA[cur][(wm + mi * 16 + lr) * 32 + lq * 8];
#pragma unroll
    for (int ni = 0; ni < 4; ++ni)
      bfr[ni] = *(const bf16x8*)&sB[cur][(wn + ni * 16 + lr) * 32 + lq * 8];
#pragma unroll
    for (int mi = 0; mi < 4; ++mi)
#pragma unroll
      for (int ni = 0; ni < 4; ++ni)
        acc[mi][ni] = __builtin_amdgcn_mfma_f32_16x16x32_bf16(
            af[mi], bfr[ni], acc[mi][ni], 0, 0, 0);
    __syncthreads();
    cur ^= 1;
  }
#undef STAGE

  if (Part) {
    float* P = Part + (size_t)blockIdx.z * M * N;
#pragma unroll
    for (int mi = 0; mi < 4; ++mi)
#pragma unroll
      for (int ni = 0; ni < 4; ++ni) {
        int col = n0 + wn + ni * 16 + lr;
#pragma unroll
        for (int r = 0; r < 4; ++r) {
          int row = m0 + wm + mi * 16 + lq * 4 + r;
          if (row < M) P[(size_t)row * N + col] = acc[mi][ni][r];
        }
      }
  } else {
    float f = alphaPtr ? tanhf(alphaPtr[0]) : 1.0f;
#pragma unroll
    for (int mi = 0; mi < 4; ++mi)
#pragma unroll
      for (int ni = 0; ni < 4; ++ni) {
        int col = n0 + wn + ni * 16 + lr;
        float bv = bias ? bias[col] : 0.f;
#pragma unroll
        for (int r = 0; r < 4; ++r) {
          int row = m0 + wm + mi * 16 + lq * 4 + r;
          if (row < M) {
            float val = acc[mi][ni][r] + bv;
            if (res) val = res[(size_t)row * N + col] + f * val;
            if (Out) Out[(size_t)row * N + col] = val;
            if (Ob)  Ob[(size_t)row * N + col] = f2b(val);
          }
        }
      }
  }
}

// ---------------- split-K reduce epilogue ----------------------------------
__global__ __launch_bounds__(256)
void splitk_epi(const float* __restrict__ Part, int nz, float* __restrict__ Out,
                ushort_t* __restrict__ Ob, int MN, int N,
                const float* __restrict__ bias, const float* __restrict__ res,
                const float* __restrict__ alphaPtr) {
  int idx = (blockIdx.x * 256 + threadIdx.x) * 4;
  if (idx >= MN) return;
  float f = alphaPtr ? tanhf(alphaPtr[0]) : 1.0f;
  float v[4] = {0.f, 0.f, 0.f, 0.f};
  for (int z = 0; z < nz; ++z) {
    float4 a = *(const float4*)&Part[(size_t)z * MN + idx];
    v[0] += a.x; v[1] += a.y; v[2] += a.z; v[3] += a.w;
  }
  if (bias) {
    int col = idx % N;
    float4 bb = *(const float4*)&bias[col];
    v[0] += bb.x; v[1] += bb.y; v[2] += bb.z; v[3] += bb.w;
  }
  if (res) {
    float4 rr = *(const float4*)&res[idx];
    v[0] = rr.x + f * v[0]; v[1] = rr.y + f * v[1];
    v[2] = rr.z + f * v[2]; v[3] = rr.w + f * v[3];
  }
  if (Out) *(float4*)&Out[idx] = make_float4(v[0], v[1], v[2], v[3]);
  if (Ob) {
    ushort4 o;
    o.x = f2b(v[0]); o.y = f2b(v[1]); o.z = f2b(v[2]); o.w = f2b(v[3]);
    *(ushort4*)&Ob[idx] = o;
  }
}

// ---------------- fused wo-epilogue + double layernorm --------------------
__global__ __launch_bounds__(256)
void woepi_ln_kernel(const float* __restrict__ Part, int nz,
                     const float* __restrict__ bias, const float* __restrict__ xres,
                     const float* __restrict__ alphaPtr, float* __restrict__ x1,
                     const float* __restrict__ g1, const float* __restrict__ b1,
                     const float* __restrict__ g2, const float* __restrict__ b2,
                     ushort_t* __restrict__ hh) {
  __shared__ float sh[4];
  int row = blockIdx.x;
  const int MN = B_DIM * N_DIM * C_DIM;
  float f = tanhf(alphaPtr[0]);
  float v[3];
#pragma unroll
  for (int j = 0; j < 3; ++j) {
    int c = threadIdx.x + j * 256;
    float s = 0.f;
    for (int z = 0; z < nz; ++z) s += Part[(size_t)z * MN + (size_t)row * C_DIM + c];
    s += bias[c];
    float xv = xres[(size_t)row * C_DIM + c] + f * s;
    x1[(size_t)row * C_DIM + c] = xv;
    v[j] = xv;
  }
  float mean = block_sum(v[0] + v[1] + v[2], sh) * (1.f / C_DIM);
  float sq = 0.f;
#pragma unroll
  for (int j = 0; j < 3; ++j) { float d = v[j] - mean; sq += d * d; }
  float rstd = rsqrtf(block_sum(sq, sh) * (1.f / C_DIM) + 1e-5f);
  float y[3];
#pragma unroll
  for (int j = 0; j < 3; ++j) {
    int c = threadIdx.x + j * 256;
    y[j] = (v[j] - mean) * rstd * g1[c] + b1[c];
  }
  float mean2 = block_sum(y[0] + y[1] + y[2], sh) * (1.f / C_DIM);
  sq = 0.f;
#pragma unroll
  for (int j = 0; j < 3; ++j) { float d = y[j] - mean2; sq += d * d; }
  float rstd2 = rsqrtf(block_sum(sq, sh) * (1.f / C_DIM) + 1e-5f);
#pragma unroll
  for (int j = 0; j < 3; ++j) {
    int c = threadIdx.x + j * 256;
    hh[(size_t)row * C_DIM + c] = f2b((y[j] - mean2) * rstd2 * g2[c] + b2[c]);
  }
}

// ---------------- V transpose: strided bf16 [key][64] -> Vt [dv][Nkp] -----
__global__ __launch_bounds__(256)
void vtrans_kernel(const ushort_t* __restrict__ V, ushort_t* __restrict__ Vt,
                   int rows_per_b, int stride, int Nk, int Nkp) {
  __shared__ ushort_t tile[64][68];
  int k0 = blockIdx.x * 64;
  int h = blockIdx.y, b = blockIdx.z;
  int t = threadIdx.x;
#pragma unroll
  for (int p = 0; p < 4; ++p) {
    int r = p * 16 + (t >> 4), c = (t & 15) * 4;
    int key = k0 + r;
    ushort4 u = make_ushort4(0, 0, 0, 0);
    if (key < Nk)
      u = *(const ushort4*)&V[((size_t)(b * rows_per_b + key)) * stride + h * 64 + c];
    *(ushort4*)&tile[r][c] = u;
  }
  __syncthreads();
  size_t base = ((size_t)(b * 12 + h)) * 64 * Nkp;
#pragma unroll
  for (int p = 0; p < 4; ++p) {
    int dv = p * 16 + (t >> 4), kc = (t & 15) * 4;
    ushort4 u;
    u.x = tile[kc + 0][dv]; u.y = tile[kc + 1][dv];
    u.z = tile[kc + 2][dv]; u.w = tile[kc + 3][dv];
    *(ushort4*)&Vt[base + (size_t)dv * Nkp + k0 + kc] = u;
  }
}

// ---------------- MFMA flash attention (R7: key-split + static-max) -------
// grid.z = B*nchunk; b = z/nchunk, kc = z%nchunk; chunk covers key tiles
// [kc*ntiles/nchunk, (kc+1)*ntiles/nchunk). Static-max softmax:
// p = exp2(s*scale - M0); no per-tile max/sum shuffles, l accumulated
// lane-locally, one butterfly at the end. Split path (Opart!=null) writes
// unnormalized fp32 O + per-row l; merge kernel combines. Single-chunk path
// (Opart==null) normalizes in-kernel and writes bf16 O.
__global__ __launch_bounds__(256)
void attn_mfma(const ushort_t* __restrict__ Q, const ushort_t* __restrict__ K,
               const ushort_t* __restrict__ Vt, ushort_t* __restrict__ O,
               float* __restrict__ Opart, float* __restrict__ lbuf,
               int q_rows_per_b, int kv_rows_per_b, int Nk, int Nkp,
               int qstride, int kstride, int nchunk) {
  __shared__ ushort_t sQ[4096];        // [2 kstep][64 q][32]
  __shared__ ushort_t sK[2][4096];     // double-buffered key tile
  __shared__ ushort_t sV[2][4096];     // double-buffered value tile (dv-major)
  __shared__ ushort_t sP[4][1024];     // per-wave P, XOR-swizzled
  const float scale = 0.18033688011112042f;   // 1/8 * log2(e)
  const float M0 = 16.0f;                     // static max (scores*scale ~ +-2)
  int t = threadIdx.x;
  int w = t >> 6, ln = t & 63;
  int col = ln & 15, quad = ln >> 4;
  int z = blockIdx.z;
  int b = z / nchunk, kc = z % nchunk;
  int h = blockIdx.y, q0 = blockIdx.x * 64;
  size_t vt_base = ((size_t)(b * 12 + h)) * 64 * Nkp;
  int ntiles = Nkp >> 6;
  int t0 = (kc * ntiles) / nchunk;
  int t1 = ((kc + 1) * ntiles) / nchunk;

#define STAGE_KV(kt_, bb_)                                                    \
  do {                                                                        \
    _Pragma("unroll") for (int s = 0; s < 2; ++s) {                           \
      int key = (kt_) * 64 + w * 16 + (ln >> 2);                              \
      g2lds16(K + (size_t)(b * kv_rows_per_b + key) * kstride                 \
                + h * 64 + s * 32 + (ln & 3) * 8,                             \
              (char*)sK[bb_] + s * 4096 + w * 1024);                          \
      int dv = w * 16 + (ln >> 2);                                            \
      g2lds16(Vt + vt_base + (size_t)dv * Nkp                                 \
                + (kt_) * 64 + s * 32 + (ln & 3) * 8,                         \
              (char*)sV[bb_] + s * 4096 + w * 1024);                          \
    }                                                                         \
  } while (0)

  // ---- stage Q + first K/V tile ----
#pragma unroll
  for (int s = 0; s < 2; ++s) {
    int r = q0 + w * 16 + (ln >> 2);
    g2lds16(Q + (size_t)(b * q_rows_per_b + r) * qstride + h * 64 + s * 32 + (ln & 3) * 8,
            (char*)sQ + s * 4096 + w * 1024);
  }
  STAGE_KV(t0, 0);
  __syncthreads();
  bf16x8 qa[2];
#pragma unroll
  for (int s = 0; s < 2; ++s)
    qa[s] = *(const bf16x8*)&sQ[s * 2048 + (w * 16 + col) * 32 + quad * 8];

  f32x4 oacc[4];
#pragma unroll
  for (int i = 0; i < 4; ++i) oacc[i] = (f32x4){0.f, 0.f, 0.f, 0.f};
  float l_i[4] = {0.f, 0.f, 0.f, 0.f};   // lane-local partial sums

  ushort_t* sPw = sP[w];
  int bb = 0;

  for (int kt = t0; kt < t1; ++kt) {
    if (kt + 1 < t1) STAGE_KV(kt + 1, bb ^ 1);   // async prefetch

    // ---- S = Q K^T ----
    f32x4 cs[4];
#pragma unroll
    for (int nblk = 0; nblk < 4; ++nblk) {
      cs[nblk] = (f32x4){0.f, 0.f, 0.f, 0.f};
#pragma unroll
      for (int s = 0; s < 2; ++s) {
        bf16x8 kb = *(const bf16x8*)&sK[bb][s * 2048 + (nblk * 16 + col) * 32 + quad * 8];
        cs[nblk] = __builtin_amdgcn_mfma_f32_16x16x32_bf16(qa[s], kb, cs[nblk], 0, 0, 0);
      }
    }
    // ---- mask partial last tile (select kills garbage/NaN) ----
    if (kt * 64 + 64 > Nk) {
#pragma unroll
      for (int nblk = 0; nblk < 4; ++nblk) {
        bool valid = (kt * 64 + nblk * 16 + col) < Nk;
#pragma unroll
        for (int r = 0; r < 4; ++r)
          cs[nblk][r] = valid ? cs[nblk][r] : -1e30f;
      }
    }
    // ---- static-max softmax: p = exp2(s*scale - M0) ----
#pragma unroll
    for (int r = 0; r < 4; ++r) {
      int row = quad * 4 + r;
#pragma unroll
      for (int nblk = 0; nblk < 4; ++nblk) {
        float p = exp2f(fmaf(cs[nblk][r], scale, -M0));
        l_i[r] += p;
        int kin = (nblk & 1) * 16 + col;
        sPw[(nblk >> 1) * 512 + row * 32 + (kin ^ (quad << 3))] = f2b(p);
      }
    }
    // ---- O += P V ----
#pragma unroll
    for (int s = 0; s < 2; ++s) {
      bf16x8 pa = *(const bf16x8*)&sPw[s * 512 + col * 32 + ((quad ^ ((col >> 2) & 3)) << 3)];
#pragma unroll
      for (int nblk = 0; nblk < 4; ++nblk) {
        bf16x8 vb = *(const bf16x8*)&sV[bb][s * 2048 + (nblk * 16 + col) * 32 + quad * 8];
        oacc[nblk] = __builtin_amdgcn_mfma_f32_16x16x32_bf16(pa, vb, oacc[nblk], 0, 0, 0);
      }
    }
    if (kt + 1 < t1) __syncthreads();   // drains prefetch + protects reuse
    bb ^= 1;
  }
#undef STAGE_KV

  // ---- epilogue ----
#pragma unroll
  for (int r = 0; r < 4; ++r) {
    float ps = l_i[r];
#pragma unroll
    for (int o = 1; o < 16; o <<= 1) ps += __shfl_xor(ps, o);
    int qglob = b * N_DIM + q0 + w * 16 + quad * 4 + r;
    if (Opart) {
      if (col == 0) lbuf[(size_t)kc * (B_DIM * N_DIM * 12) + (size_t)qglob * 12 + h] = ps;
      float* op = Opart + (size_t)kc * MNX + (size_t)qglob * C_DIM + h * 64;
#pragma unroll
      for (int nblk = 0; nblk < 4; ++nblk)
        op[nblk * 16 + col] = oacc[nblk][r];
    } else {
      float inv = 1.f / ps;
#pragma unroll
      for (int nblk = 0; nblk < 4; ++nblk)
        O[(size_t)qglob * C_DIM + h * 64 + nblk * 16 + col] = f2b(oacc[nblk][r] * inv);
    }
  }
}

// ---------------- merge key-split attention partials ----------------------
__global__ __launch_bounds__(256)
void attn_merge(const float* __restrict__ Opart, const float* __restrict__ lbuf,
                ushort_t* __restrict__ Ob, int nchunk) {
  int idx = (blockIdx.x * 256 + threadIdx.x) * 4;
  if (idx >= MNX) return;
  int row = idx / C_DIM, c = idx % C_DIM;
  int h = c >> 6;
  float l = 0.f;
  float v[4] = {0.f, 0.f, 0.f, 0.f};
  for (int kc = 0; kc < nchunk; ++kc) {
    l += lbuf[(size_t)kc * (B_DIM * N_DIM * 12) + (size_t)row * 12 + h];
    float4 p = *(const float4*)&Opart[(size_t)kc * MNX + idx];
    v[0] += p.x; v[1] += p.y; v[2] += p.z; v[3] += p.w;
  }
  float inv = 1.f / l;
  ushort4 o;
  o.x = f2b(v[0] * inv); o.y = f2b(v[1] * inv);
  o.z = f2b(v[2] * inv); o.w = f2b(v[3] * inv);
  *(ushort4*)&Ob[idx] = o;
}

// ---------------- GEGLU ----------------------------------------------------
__global__ __launch_bounds__(256)
void geglu_kernel(const ushort_t* __restrict__ tbuf, ushort_t* __restrict__ g) {
  int idx = blockIdx.x * 256 + threadIdx.x;
  int r = idx / INNER, c = idx % INNER;
  float a = b2f(tbuf[(size_t)r * (2 * INNER) + c]);
  float x = b2f(tbuf[(size_t)r * (2 * INNER) + INNER + c]);
  float ge = 0.5f * x * (1.f + erff(x * 0.70710678118654752f));
  g[idx] = f2b(a * ge);
}

// ---------------- text gather ----------------------------------------------
__global__ __launch_bounds__(256)
void gather_text_kernel(const float* __restrict__ enc, ushort_t* __restrict__ out) {
  int r = blockIdx.x;
  int bb = r / TEXT_LEN, j = r % TEXT_LEN;
  const float* src = enc + ((size_t)bb * L_DIM + j) * C_DIM;
  ushort_t* dst = out + (size_t)r * C_DIM;
#pragma unroll
  for (int l = 0; l < 3; ++l) {
    int c = threadIdx.x + l * 256;
    dst[c] = f2b(src[c]);
  }
}

// ---------------------------------------------------------------------------
extern "C" void kernel_launch(void* const* d_in, const int* in_sizes, int n_in,
                              void* d_out, int out_size, void* d_ws, size_t ws_size,
                              hipStream_t stream) {
  const float* x        = (const float*)d_in[0];
  const float* enc      = (const float*)d_in[1];
  const float* ln1_g    = (const float*)d_in[2];
  const float* ln1_b    = (const float*)d_in[3];
  const float* ln2_g    = (const float*)d_in[4];
  const float* ln2_b    = (const float*)d_in[5];
  const float* sa_wq    = (const float*)d_in[6];
  const float* sa_wk    = (const float*)d_in[7];
  const float* sa_wv    = (const float*)d_in[8];
  const float* sa_wo    = (const float*)d_in[9];
  const float* sa_wo_b  = (const float*)d_in[10];
  const float* ff_ln_g  = (const float*)d_in[11];
  const float* ff_ln_b  = (const float*)d_in[12];
  const float* ff_w1    = (const float*)d_in[13];
  const float* ff_w2    = (const float*)d_in[14];
  const float* a_attn   = (const float*)d_in[15];
  const float* a_dense  = (const float*)d_in[16];
  const float* ca_wq    = (const float*)d_in[17];
  const float* ca_wk    = (const float*)d_in[18];
  const float* ca_wv    = (const float*)d_in[19];
  const float* ca_wo    = (const float*)d_in[20];
  const float* ca_wo_b  = (const float*)d_in[21];

  char* ws = (char*)d_ws;
  float*    x1     = (float*)(ws + WX1);
  float*    x2     = (float*)(ws + WX2);
  ushort_t* qkv_b  = (ushort_t*)(ws + WQKV);
  ushort_t* q2b    = (ushort_t*)(ws + WQKV);
  ushort_t* kv2b   = (ushort_t*)(ws + WQKV + 3145728u);
  ushort_t* comb_b = (ushort_t*)(ws + WBB1);
  ushort_t* tbuf_b = (ushort_t*)(ws + WBB1);
  ushort_t* attn_b = (ushort_t*)(ws + WATTN);
  float*    opart  = (float*)(ws + WOPART);
  float*    lbuf   = (float*)(ws + WLBUF);
  ushort_t* g_b    = (ushort_t*)(ws + WG);
  ushort_t* hh     = (ushort_t*)(ws + WS1);
  ushort_t* x2b    = (ushort_t*)(ws + WS1);
  ushort_t* text_b = (ushort_t*)(ws + WTEXT);
  ushort_t* attn2b = (ushort_t*)(ws + WATT2);
  ushort_t* wqkv_t = (ushort_t*)(ws + WWQKV);
  ushort_t* wo_t   = (ushort_t*)(ws + WWO);
  ushort_t* w1_t   = (ushort_t*)(ws + WW1);
  ushort_t* w2_t   = (ushort_t*)(ws + WW2);
  ushort_t* cawq_t = (ushort_t*)(ws + WCAWQ);
  ushort_t* cakv_t = (ushort_t*)(ws + WCAKV);
  ushort_t* cawo_t = (ushort_t*)(ws + WCAWO);
  ushort_t* vt1    = (ushort_t*)(ws + WVT1);
  ushort_t* vt2    = (ushort_t*)(ws + WVT2);
  float* part = (float*)(ws + WPART);
  float* out = (float*)d_out;

  const int Mc = B_DIM * NC_DIM;   // 2080
  const int Mx = B_DIM * N_DIM;    // 2048
  const int Mt = B_DIM * TEXT_LEN; // 154
  const int MNx = MNX;

  // ---- batched weight transposes ----
  WtDesc wd;
  const float* srcs[10] = {sa_wq, sa_wk, sa_wv, sa_wo, ca_wq, ca_wk, ca_wv, ca_wo, ff_w1, ff_w2};
  ushort_t* dsts[10] = {wqkv_t, wqkv_t + 589824, wqkv_t + 2 * 589824, wo_t,
                        cawq_t, cakv_t, cakv_t + 589824, cawo_t, w1_t, w2_t};
  int Ks[10] = {768, 768, 768, 768, 768, 768, 768, 768, 768, 3072};
  int Ns[10] = {768, 768, 768, 768, 768, 768, 768, 768, 6144, 768};
  int total = 0;
  for (int j = 0; j < 10; ++j) {
    wd.src[j] = srcs[j]; wd.dst[j] = dsts[j];
    wd.K[j] = Ks[j]; wd.N[j] = Ns[j];
    wd.tilesX[j] = Ns[j] / 64;
    wd.start[j] = total;
    total += (Ns[j] / 64) * (Ks[j] / 64);
  }
  wd.start[10] = total;   // 2880

  wtrans_batched<<<total, 256, 0, stream>>>(wd);
  ln_concat_kernel<<<Mc, 256, 0, stream>>>(x, enc, ln1_g, ln1_b, comb_b);
  gemm_bf16<<<dim3(18, 17, 1), 256, 0, stream>>>(
      comb_b, wqkv_t, nullptr, qkv_b, nullptr, Mc, 2304, 768, 768,
      nullptr, nullptr, nullptr);
  vtrans_kernel<<<dim3(17, 12, B_DIM), 256, 0, stream>>>(
      qkv_b + 1536, vt1, NC_DIM, 2304, NC_DIM, 1088);
  // self-attn: 4-way key split -> fp32 partials + l, then merge
  attn_mfma<<<dim3(N_DIM / 64, 12, B_DIM * 4), 256, 0, stream>>>(
      qkv_b + 0, qkv_b + 768, vt1, nullptr, opart, lbuf,
      NC_DIM, NC_DIM, NC_DIM, 1088, 2304, 2304, 4);
  attn_merge<<<MNx / 1024, 256, 0, stream>>>(opart, lbuf, attn_b, 4);
  // wo: split-K 4 x 192 -> partials -> fused epilogue+double-LN
  gemm_bf16<<<dim3(6, 16, 4), 256, 0, stream>>>(
      attn_b, wo_t, nullptr, nullptr, part, Mx, 768, 768, 192,
      nullptr, nullptr, nullptr);
  woepi_ln_kernel<<<Mx, 256, 0, stream>>>(
      part, 4, sa_wo_b, x, a_attn, x1, ln2_g, ln2_b, ff_ln_g, ff_ln_b, hh);
  gemm_bf16<<<dim3(48, 16, 1), 256, 0, stream>>>(
      hh, w1_t, nullptr, tbuf_b, nullptr, Mx, 6144, 768, 768,
      nullptr, nullptr, nullptr);
  geglu_kernel<<<(Mx * INNER) / 256, 256, 0, stream>>>(tbuf_b, g_b);
  // ff2: split-K 4 x 768
  gemm_bf16<<<dim3(6, 16, 4), 256, 0, stream>>>(
      g_b, w2_t, nullptr, nullptr, part, Mx, 768, 3072, 768,
      nullptr, nullptr, nullptr);
  splitk_epi<<<MNx / 1024, 256, 0, stream>>>(
      part, 4, x2, x2b, MNx, 768, nullptr, x1, a_dense);
  gather_text_kernel<<<Mt, 256, 0, stream>>>(enc, text_b);
  // q2: split-K 4 x 192
  gemm_bf16<<<dim3(6, 16, 4), 256, 0, stream>>>(
      x2b, cawq_t, nullptr, nullptr, part, Mx, 768, 768, 192,
      nullptr, nullptr, nullptr);
  splitk_epi<<<MNx / 1024, 256, 0, stream>>>(
      part, 4, nullptr, q2b, MNx, 768, nullptr, nullptr, nullptr);
  gemm_bf16<<<dim3(12, 2, 1), 256, 0, stream>>>(
      text_b, cakv_t, nullptr, kv2b, nullptr, Mt, 1536, 768, 768,
      nullptr, nullptr, nullptr);
  vtrans_kernel<<<dim3(2, 12, B_DIM), 256, 0, stream>>>(
      kv2b + 768, vt2, TEXT_LEN, 1536, TEXT_LEN, 128);
  // cross-attn: single chunk, in-kernel normalize
  attn_mfma<<<dim3(N_DIM / 64, 12, B_DIM), 256, 0, stream>>>(
      q2b, kv2b + 0, vt2, attn2b, nullptr, nullptr,
      N_DIM, TEXT_LEN, TEXT_LEN, 128, 768, 1536, 1);
  // final: split-K 4 x 192
  gemm_bf16<<<dim3(6, 16, 4), 256, 0, stream>>>(
      attn2b, cawo_t, nullptr, nullptr, part, Mx, 768, 768, 192,
      nullptr, nullptr, nullptr);
  splitk_epi<<<MNx / 1024, 256, 0, stream>>>(
      part, 4, out, nullptr, MNx, 768, ca_wo_b, x2, nullptr);
}